// Round 1
// baseline (392.602 us; speedup 1.0000x reference)
//
#include <hip/hip_runtime.h>
#include <math.h>

// Problem constants (B=8, V=256, H=128)
#define BV 2048            // B*V rows
#define V_ 256
#define H_ 128

__device__ __forceinline__ float silu_f(float x) {
    return x / (1.0f + expf(-x));
}

// ---------------------------------------------------------------------------
// k1: h0 = silu(h @ W_pre + b_pre), skip = silu(h @ W_skip + b_skip)
// 8 rows per block, 256 threads. h tile staged in LDS (broadcast reads),
// W columns streamed coalesced from L2.
// ---------------------------------------------------------------------------
__global__ __launch_bounds__(256) void k1_pre_skip(
    const float* __restrict__ h,
    const float* __restrict__ W_pre, const float* __restrict__ b_pre,
    const float* __restrict__ W_skip, const float* __restrict__ b_skip,
    float* __restrict__ h0ws, float* __restrict__ skipws)
{
    const int t = threadIdx.x;
    const int rbase = blockIdx.x * 8;
    __shared__ float s_h[8 * H_];
    #pragma unroll
    for (int q = 0; q < 4; ++q) {
        int flat = q * 256 + t;                 // [0, 1024)
        s_h[flat] = h[rbase * H_ + flat];
    }
    __syncthreads();

    const int c  = t & 127;
    const int r0 = (t >> 7) * 4;                // 0 or 4
    float a0[4] = {0.f, 0.f, 0.f, 0.f};
    float a1[4] = {0.f, 0.f, 0.f, 0.f};
    #pragma unroll 4
    for (int k = 0; k < H_; ++k) {
        float w0 = W_pre[k * H_ + c];
        float w1 = W_skip[k * H_ + c];
        #pragma unroll
        for (int r = 0; r < 4; ++r) {
            float hv = s_h[(r0 + r) * H_ + k];
            a0[r] += hv * w0;
            a1[r] += hv * w1;
        }
    }
    const float bp = b_pre[c], bs = b_skip[c];
    #pragma unroll
    for (int r = 0; r < 4; ++r) {
        int row = rbase + r0 + r;
        h0ws[row * H_ + c]   = silu_f(a0[r] + bp);
        skipws[row * H_ + c] = silu_f(a1[r] + bs);
    }
}

// ---------------------------------------------------------------------------
// k2: neigh[b,i,h] = max_j ( graph[b,i,j]!=0 ? 0 : e[b,i,j,h]*h0[b,j,h] )
// One block per (b,i). Compact the unmasked j list (ballot+popcount), pad to
// a multiple of 8 with a duplicate index (max is idempotent) so the streaming
// loop is branch-free. Thread t: h4 = t%32 (float4 lane), jg = t/32 (j group).
// Skips ~50% of the 268 MB e stream.
// ---------------------------------------------------------------------------
__global__ __launch_bounds__(256, 4) void k2_edge_max(
    const float4* __restrict__ e4,
    const int* __restrict__ graph,
    const float4* __restrict__ h04,
    float* __restrict__ nws)
{
    const int t  = threadIdx.x;
    const int bi = blockIdx.x;          // b*256 + i
    const int b  = bi >> 8;

    __shared__ int   s_list[V_];
    __shared__ int   s_wcnt[4];
    __shared__ float s_red[8 * H_];

    // --- compact unmasked j's ---
    const int  g    = graph[bi * V_ + t];
    const bool keep = (g == 0);
    unsigned long long bal = __ballot(keep);
    const int lane = t & 63;
    const int wv   = t >> 6;
    if (lane == 0) s_wcnt[wv] = __popcll(bal);
    __syncthreads();
    const int count = s_wcnt[0] + s_wcnt[1] + s_wcnt[2] + s_wcnt[3];
    int off = 0;
    for (int w = 0; w < wv; ++w) off += s_wcnt[w];
    if (keep) s_list[off + __popcll(bal & ((1ull << lane) - 1ull))] = t;
    __syncthreads();
    // pad to multiple of 8 with duplicates (max-idempotent)
    const int itmax = (count + 7) >> 3;
    const int itpad = itmax << 3;
    if (count > 0 && t >= count && t < itpad) s_list[t] = s_list[0];
    __syncthreads();

    // --- stream unmasked e rows ---
    const int h4 = t & 31;
    const int jg = t >> 5;
    const float4* __restrict__ ep = e4 + (size_t)bi * (V_ * 32);
    const float4* __restrict__ hp = h04 + (size_t)(b << 8) * 32;

    float4 vmax = make_float4(-INFINITY, -INFINITY, -INFINITY, -INFINITY);
    #pragma unroll 4
    for (int it = 0; it < itmax; ++it) {
        int j = s_list[(it << 3) + jg];
        float4 ev = ep[j * 32 + h4];
        float4 hv = hp[j * 32 + h4];
        vmax.x = fmaxf(vmax.x, ev.x * hv.x);
        vmax.y = fmaxf(vmax.y, ev.y * hv.y);
        vmax.z = fmaxf(vmax.z, ev.z * hv.z);
        vmax.w = fmaxf(vmax.w, ev.w * hv.w);
    }

    // --- reduce the 8 j-groups ---
    *reinterpret_cast<float4*>(&s_red[jg * H_ + h4 * 4]) = vmax;
    __syncthreads();
    if (t < H_) {
        float m = s_red[t];
        #pragma unroll
        for (int gg = 1; gg < 8; ++gg) m = fmaxf(m, s_red[gg * H_ + t]);
        if (count < V_) m = fmaxf(m, 0.0f);   // masked entries contribute 0
        nws[bi * H_ + t] = m;                  // count==0 -> max(-inf,0)=0
    }
}

// ---------------------------------------------------------------------------
// k3: h1 = silu([h0, neigh] @ W_post + b_post); out = silu(skip + h1)
// 8 rows per block; h_cat tile in LDS (broadcast), W_post streamed from L2.
// ---------------------------------------------------------------------------
__global__ __launch_bounds__(256) void k3_post(
    const float* __restrict__ h0ws,
    const float* __restrict__ nws,
    const float* __restrict__ skipws,
    const float* __restrict__ W_post, const float* __restrict__ b_post,
    float* __restrict__ out)
{
    const int t = threadIdx.x;
    const int rbase = blockIdx.x * 8;
    __shared__ float s_cat[8 * 256];
    #pragma unroll
    for (int q = 0; q < 8; ++q) {
        int flat = q * 256 + t;                 // [0, 2048)
        int row  = flat >> 8;
        int k    = flat & 255;
        float v  = (k < H_) ? h0ws[(rbase + row) * H_ + k]
                            : nws[(rbase + row) * H_ + (k - H_)];
        s_cat[flat] = v;
    }
    __syncthreads();

    const int c  = t & 127;
    const int r0 = (t >> 7) * 4;
    float acc[4] = {0.f, 0.f, 0.f, 0.f};
    #pragma unroll 4
    for (int k = 0; k < 256; ++k) {
        float w = W_post[k * H_ + c];
        #pragma unroll
        for (int r = 0; r < 4; ++r)
            acc[r] += s_cat[(r0 + r) * 256 + k] * w;
    }
    const float bp = b_post[c];
    #pragma unroll
    for (int r = 0; r < 4; ++r) {
        int row = rbase + r0 + r;
        float h1 = silu_f(acc[r] + bp);
        out[row * H_ + c] = silu_f(skipws[row * H_ + c] + h1);
    }
}

// ---------------------------------------------------------------------------
extern "C" void kernel_launch(void* const* d_in, const int* in_sizes, int n_in,
                              void* d_out, int out_size, void* d_ws, size_t ws_size,
                              hipStream_t stream)
{
    const float* h      = (const float*)d_in[0];
    const float* e      = (const float*)d_in[1];
    const int*   graph  = (const int*)  d_in[2];
    const float* W_pre  = (const float*)d_in[3];
    const float* b_pre  = (const float*)d_in[4];
    const float* W_post = (const float*)d_in[5];
    const float* b_post = (const float*)d_in[6];
    const float* W_skip = (const float*)d_in[7];
    const float* b_skip = (const float*)d_in[8];
    float* out = (float*)d_out;

    float* ws     = (float*)d_ws;
    float* h0ws   = ws;                    // BV*H floats = 1 MB
    float* skipws = ws + BV * H_;          // 1 MB
    float* nws    = ws + 2 * BV * H_;      // 1 MB

    k1_pre_skip<<<BV / 8, 256, 0, stream>>>(h, W_pre, b_pre, W_skip, b_skip,
                                            h0ws, skipws);
    k2_edge_max<<<BV, 256, 0, stream>>>((const float4*)e, graph,
                                        (const float4*)h0ws, nws);
    k3_post<<<BV / 8, 256, 0, stream>>>(h0ws, nws, skipws, W_post, b_post, out);
}

// Round 2
// 391.579 us; speedup vs baseline: 1.0026x; 1.0026x over previous
//
#include <hip/hip_runtime.h>
#include <math.h>

// Problem constants (B=8, V=256, H=128)
#define BV 2048            // B*V rows
#define V_ 256
#define H_ 128

__device__ __forceinline__ float silu_f(float x) {
    return x / (1.0f + expf(-x));
}

// ---------------------------------------------------------------------------
// k1: h0 = silu(h @ W_pre + b_pre), skip = silu(h @ W_skip + b_skip)
// 8 rows per block, 256 threads. h tile staged in LDS (broadcast reads),
// W columns streamed coalesced from L2.
// ---------------------------------------------------------------------------
__global__ __launch_bounds__(256) void k1_pre_skip(
    const float* __restrict__ h,
    const float* __restrict__ W_pre, const float* __restrict__ b_pre,
    const float* __restrict__ W_skip, const float* __restrict__ b_skip,
    float* __restrict__ h0ws, float* __restrict__ skipws)
{
    const int t = threadIdx.x;
    const int rbase = blockIdx.x * 8;
    __shared__ float s_h[8 * H_];
    #pragma unroll
    for (int q = 0; q < 4; ++q) {
        int flat = q * 256 + t;                 // [0, 1024)
        s_h[flat] = h[rbase * H_ + flat];
    }
    __syncthreads();

    const int c  = t & 127;
    const int r0 = (t >> 7) * 4;                // 0 or 4
    float a0[4] = {0.f, 0.f, 0.f, 0.f};
    float a1[4] = {0.f, 0.f, 0.f, 0.f};
    #pragma unroll 4
    for (int k = 0; k < H_; ++k) {
        float w0 = W_pre[k * H_ + c];
        float w1 = W_skip[k * H_ + c];
        #pragma unroll
        for (int r = 0; r < 4; ++r) {
            float hv = s_h[(r0 + r) * H_ + k];
            a0[r] += hv * w0;
            a1[r] += hv * w1;
        }
    }
    const float bp = b_pre[c], bs = b_skip[c];
    #pragma unroll
    for (int r = 0; r < 4; ++r) {
        int row = rbase + r0 + r;
        h0ws[row * H_ + c]   = silu_f(a0[r] + bp);
        skipws[row * H_ + c] = silu_f(a1[r] + bs);
    }
}

// ---------------------------------------------------------------------------
// k2: neigh[b,i,h] = max_j ( graph[b,i,j]!=0 ? 0 : e[b,i,j,h]*h0[b,j,h] )
// One block per (b,i). Compact unmasked j's (ballot+popcount), then TRANSPOSE
// the list so group jg's next 4 indices are one broadcast int4 LDS read.
// Thread t: h4 = t%32 (float4 lane), jg = t/32 (8 j-groups). Each chunk
// issues 8 float4 e-loads + 8 float4 h0-loads (h0 is L2-resident) before any
// vmcnt wait -> ~512 B/thread in flight with unroll 2. Skips ~50% of the
// 268 MB e stream (masked rows contribute 0, folded in as final max(.,0)).
// ---------------------------------------------------------------------------
__global__ __launch_bounds__(256, 4) void k2_edge_max(
    const float4* __restrict__ e4,
    const int* __restrict__ graph,
    const float4* __restrict__ h04,
    float* __restrict__ nws)
{
    const int t  = threadIdx.x;
    const int bi = blockIdx.x;          // b*256 + i
    const int b  = bi >> 8;

    __shared__ int   s_list[V_];
    __shared__ int   s_listT[V_];       // [jg][it] transposed, int4-readable
    __shared__ int   s_wcnt[4];
    __shared__ float s_red[8 * H_];

    // --- compact unmasked j's ---
    const int  g    = graph[bi * V_ + t];
    const bool keep = (g == 0);
    unsigned long long bal = __ballot(keep);
    const int lane = t & 63;
    const int wv   = t >> 6;
    if (lane == 0) s_wcnt[wv] = __popcll(bal);
    __syncthreads();
    const int count = s_wcnt[0] + s_wcnt[1] + s_wcnt[2] + s_wcnt[3];
    int off = 0;
    for (int w = 0; w < wv; ++w) off += s_wcnt[w];
    if (keep) s_list[off + __popcll(bal & ((1ull << lane) - 1ull))] = t;
    __syncthreads();

    // --- transpose + pad to multiple of 32 (duplicates are max-idempotent) ---
    const int j0  = (count > 0) ? s_list[0] : 0;
    {
        const int jgT = t >> 5;          // 0..7
        const int itT = t & 31;          // 0..31
        const int idx = itT * 8 + jgT;   // position in compacted order
        s_listT[jgT * 32 + itT] = (idx < count) ? s_list[idx] : j0;
    }
    __syncthreads();

    // --- stream unmasked e rows ---
    const int h4 = t & 31;
    const int jg = t >> 5;
    const float4* __restrict__ ep = e4 + (size_t)bi * (V_ * 32) + h4;
    const float4* __restrict__ hp = h04 + ((size_t)(b << 8) * 32) + h4;
    const int4*   __restrict__ lt = reinterpret_cast<const int4*>(s_listT) + jg * 8;

    const int chunks = (count + 31) >> 5;   // each chunk = 4 j's per group
    float4 vmax = make_float4(-INFINITY, -INFINITY, -INFINITY, -INFINITY);
    #pragma unroll 2
    for (int c0 = 0; c0 < chunks; ++c0) {
        int4 j4 = lt[c0];
        float4 ea = ep[j4.x * 32];
        float4 eb = ep[j4.y * 32];
        float4 ec = ep[j4.z * 32];
        float4 ed = ep[j4.w * 32];
        float4 ha = hp[j4.x * 32];
        float4 hb = hp[j4.y * 32];
        float4 hc = hp[j4.z * 32];
        float4 hd = hp[j4.w * 32];
        vmax.x = fmaxf(vmax.x, ea.x * ha.x); vmax.y = fmaxf(vmax.y, ea.y * ha.y);
        vmax.z = fmaxf(vmax.z, ea.z * ha.z); vmax.w = fmaxf(vmax.w, ea.w * ha.w);
        vmax.x = fmaxf(vmax.x, eb.x * hb.x); vmax.y = fmaxf(vmax.y, eb.y * hb.y);
        vmax.z = fmaxf(vmax.z, eb.z * hb.z); vmax.w = fmaxf(vmax.w, eb.w * hb.w);
        vmax.x = fmaxf(vmax.x, ec.x * hc.x); vmax.y = fmaxf(vmax.y, ec.y * hc.y);
        vmax.z = fmaxf(vmax.z, ec.z * hc.z); vmax.w = fmaxf(vmax.w, ec.w * hc.w);
        vmax.x = fmaxf(vmax.x, ed.x * hd.x); vmax.y = fmaxf(vmax.y, ed.y * hd.y);
        vmax.z = fmaxf(vmax.z, ed.z * hd.z); vmax.w = fmaxf(vmax.w, ed.w * hd.w);
    }

    // --- reduce the 8 j-groups ---
    *reinterpret_cast<float4*>(&s_red[jg * H_ + h4 * 4]) = vmax;
    __syncthreads();
    if (t < H_) {
        float m = s_red[t];
        #pragma unroll
        for (int gg = 1; gg < 8; ++gg) m = fmaxf(m, s_red[gg * H_ + t]);
        if (count < V_) m = fmaxf(m, 0.0f);   // masked entries contribute 0
        nws[bi * H_ + t] = m;                  // count==0 -> max(-inf,0)=0
    }
}

// ---------------------------------------------------------------------------
// k3: h1 = silu([h0, neigh] @ W_post + b_post); out = silu(skip + h1)
// 8 rows per block; h_cat tile in LDS (broadcast), W_post streamed from L2.
// ---------------------------------------------------------------------------
__global__ __launch_bounds__(256) void k3_post(
    const float* __restrict__ h0ws,
    const float* __restrict__ nws,
    const float* __restrict__ skipws,
    const float* __restrict__ W_post, const float* __restrict__ b_post,
    float* __restrict__ out)
{
    const int t = threadIdx.x;
    const int rbase = blockIdx.x * 8;
    __shared__ float s_cat[8 * 256];
    #pragma unroll
    for (int q = 0; q < 8; ++q) {
        int flat = q * 256 + t;                 // [0, 2048)
        int row  = flat >> 8;
        int k    = flat & 255;
        float v  = (k < H_) ? h0ws[(rbase + row) * H_ + k]
                            : nws[(rbase + row) * H_ + (k - H_)];
        s_cat[flat] = v;
    }
    __syncthreads();

    const int c  = t & 127;
    const int r0 = (t >> 7) * 4;
    float acc[4] = {0.f, 0.f, 0.f, 0.f};
    #pragma unroll 4
    for (int k = 0; k < 256; ++k) {
        float w = W_post[k * H_ + c];
        #pragma unroll
        for (int r = 0; r < 4; ++r)
            acc[r] += s_cat[(r0 + r) * 256 + k] * w;
    }
    const float bp = b_post[c];
    #pragma unroll
    for (int r = 0; r < 4; ++r) {
        int row = rbase + r0 + r;
        float h1 = silu_f(acc[r] + bp);
        out[row * H_ + c] = silu_f(skipws[row * H_ + c] + h1);
    }
}

// ---------------------------------------------------------------------------
extern "C" void kernel_launch(void* const* d_in, const int* in_sizes, int n_in,
                              void* d_out, int out_size, void* d_ws, size_t ws_size,
                              hipStream_t stream)
{
    const float* h      = (const float*)d_in[0];
    const float* e      = (const float*)d_in[1];
    const int*   graph  = (const int*)  d_in[2];
    const float* W_pre  = (const float*)d_in[3];
    const float* b_pre  = (const float*)d_in[4];
    const float* W_post = (const float*)d_in[5];
    const float* b_post = (const float*)d_in[6];
    const float* W_skip = (const float*)d_in[7];
    const float* b_skip = (const float*)d_in[8];
    float* out = (float*)d_out;

    float* ws     = (float*)d_ws;
    float* h0ws   = ws;                    // BV*H floats = 1 MB
    float* skipws = ws + BV * H_;          // 1 MB
    float* nws    = ws + 2 * BV * H_;      // 1 MB

    k1_pre_skip<<<BV / 8, 256, 0, stream>>>(h, W_pre, b_pre, W_skip, b_skip,
                                            h0ws, skipws);
    k2_edge_max<<<BV, 256, 0, stream>>>((const float4*)e, graph,
                                        (const float4*)h0ws, nws);
    k3_post<<<BV / 8, 256, 0, stream>>>(h0ws, nws, skipws, W_post, b_post, out);
}